// Round 3
// baseline (496.961 us; speedup 1.0000x reference)
//
#include <hip/hip_runtime.h>

// obj = (99*sum_t ||c_t||^2 + ||sum_t c_t||^2)/100 (Parseval over the 100
// samples = 99th roots of unity, z=1 double-counted), c_0 = D_F,
// c_{k+1} = E_k = C_F A_F^k B_F - C A^k B, B = eye(256,128).
// DOUBLE-STEP with bf16 constant matrices:
//   pre1: split-K partials of A2=AF^2, W1=AF*BF, AH2=A^2 (fp32 acc, bf16 B)
//   pre2: resolve partials; convert A2,W1,AH2,BF,A to packed bf16 (r|i<<16)
//   dstep s: Ee_s = QF*BFb - QH[:,:128]; Eo_s = QF*W1b - QH*Ab[:,:128];
//            QF <- QF*A2b; QH <- QH*AH2b   (Q fp32, B-slabs bf16)
// This revision: single PERSISTENT kernel (plain launch, NOT cooperative —
// hipLaunchCooperativeKernel silently rejected grid 512 last round: output
// stayed memset-zero) with a hand-rolled sense-reversing grid barrier.
// Residency guaranteed: __launch_bounds__(256,2) + 55.25 KB LDS -> 2
// blocks/CU capacity -> all 512 blocks co-resident. Cross-XCD coherence via
// __threadfence_system() (L2 writeback+inv) around each barrier. Barrier
// counters + S1/S2/SD/tick zeroed by hipMemsetAsync before the kernel
// (workspace is re-poisoned every iteration). GEMM bodies identical to the
// round-1 passing kernel.

#define KSTEPS 4   // double-steps -> E_0..E_7
#define NBLK 512

struct Params {
    const float *AFr, *AFi, *Ar, *Ai, *BFr, *BFi, *CFr, *CFi, *Cr, *Ci, *DFr, *DFi;
    float2 *A2p, *W1p, *AH2p;                 // pre1 split-K partials (x4)
    unsigned int *A2b, *W1b, *AH2b, *BFb, *Ab;  // packed bf16 constants
    float2 *QFp0, *QFp1, *QHp0, *QHp1, *Eep0, *Eep1, *Eop0, *Eop1, *Sm;
    float *S1, *S2, *SD, *out;
    unsigned int *tick, *bcnt, *bgen;
};

__device__ __forceinline__ unsigned int f2bf2(float r, float i) {
    unsigned int ur = __float_as_uint(r); ur = (ur + 0x7fffu + ((ur >> 16) & 1u)) >> 16;
    unsigned int ui = __float_as_uint(i); ui = (ui + 0x7fffu + ((ui >> 16) & 1u)) >> 16;
    return ur | (ui << 16);
}

// Sense-reversing grid barrier. All NBLK blocks call this the same number of
// times. System-scope fences provide cross-XCD L2 writeback/invalidate.
__device__ __forceinline__ void grid_barrier(unsigned int* cnt, unsigned int* gen) {
    __syncthreads();
    if (threadIdx.x == 0) {
        unsigned int g = __hip_atomic_load(gen, __ATOMIC_RELAXED, __HIP_MEMORY_SCOPE_AGENT);
        __threadfence_system();   // release: drain + write back dirty L2
        unsigned int arrived = __hip_atomic_fetch_add(cnt, 1u, __ATOMIC_ACQ_REL,
                                                      __HIP_MEMORY_SCOPE_AGENT);
        if (arrived == NBLK - 1u) {
            __hip_atomic_store(cnt, 0u, __ATOMIC_RELAXED, __HIP_MEMORY_SCOPE_AGENT);
            __hip_atomic_fetch_add(gen, 1u, __ATOMIC_RELEASE, __HIP_MEMORY_SCOPE_AGENT);
        } else {
            while (__hip_atomic_load(gen, __ATOMIC_RELAXED, __HIP_MEMORY_SCOPE_AGENT) == g)
                __builtin_amdgcn_s_sleep(1);
        }
        __threadfence_system();   // acquire: invalidate L2 so fresh data is refetched
    }
    __syncthreads();
}

__device__ __forceinline__ float block_reduce(float v, float* red, int tid) {
    red[tid] = v;
    __syncthreads();
    for (int off = 128; off > 0; off >>= 1) {
        if (tid < off) red[tid] += red[tid + off];
        __syncthreads();
    }
    float r = red[0];
    __syncthreads();
    return r;
}

// Barrier-free complex inner product: Q (fp32, LDS broadcast rows) x
// B (bf16-packed, LDS persistent slab), 2x2 output tile per thread.
template<int KD>
__device__ __forceinline__ void cmul_inner(const unsigned int* __restrict__ sBu,
                                           const float2 (*__restrict__ sQ)[8],
                                           int w, int lane, float acc[8]) {
    #pragma unroll 8
    for (int kk = 0; kk < KD; ++kk) {
        float4 qv = *(const float4*)&sQ[kk][2 * w];
        uint2 bu = *(const uint2*)&sBu[(kk << 7) + 2 * lane];
        float b0r = __uint_as_float(bu.x << 16);
        float b0i = __uint_as_float(bu.x & 0xffff0000u);
        float b1r = __uint_as_float(bu.y << 16);
        float b1i = __uint_as_float(bu.y & 0xffff0000u);
        acc[0] += qv.x * b0r - qv.y * b0i;  acc[1] += qv.x * b0i + qv.y * b0r;
        acc[2] += qv.x * b1r - qv.y * b1i;  acc[3] += qv.x * b1i + qv.y * b1r;
        acc[4] += qv.z * b0r - qv.w * b0i;  acc[5] += qv.z * b0i + qv.w * b0r;
        acc[6] += qv.z * b1r - qv.w * b1i;  acc[7] += qv.z * b1i + qv.w * b1r;
    }
}

// ---------------- pre1 task body: one split-K partial tile ------------------
template<int KD>
__device__ __forceinline__ void pre1_body(const float* __restrict__ Qr_,
        const float* __restrict__ Qi_, const float* __restrict__ Br_,
        const float* __restrict__ Bi_, int Wq, int Wb, int rg, int c0, int k0,
        unsigned int* sBu, float2 (*sQ)[8], int w, int lane, float acc[8]) {
    const int tid = threadIdx.x;
    // stage whole B slab, converting fp32 pairs -> packed bf16 on the fly
    for (int slot = tid; slot < KD * 32; slot += 256) {
        int row = slot >> 5, cq = (slot & 31) << 2;
        int g = (k0 + row) * Wb + c0 + cq;
        float4 vr = *(const float4*)&Br_[g];
        float4 vi = *(const float4*)&Bi_[g];
        *(uint4*)&sBu[(row << 7) + cq] = make_uint4(
            f2bf2(vr.x, vi.x), f2bf2(vr.y, vi.y), f2bf2(vr.z, vi.z), f2bf2(vr.w, vi.w));
    }
    // stage Q rows rg*8..+7 over [k0,k0+KD)
    for (int slot = tid; slot < 8 * KD; slot += 256) {
        int row = slot / KD, kk = slot - row * KD;
        int g = (rg * 8 + row) * Wq + k0 + kk;
        sQ[kk][row] = make_float2(Qr_[g], Qi_[g]);
    }
    __syncthreads();
    cmul_inner<KD>(sBu, sQ, w, lane, acc);
}

// ---------------- double-step GEMM: fp32 Q x bf16 B, 2x2 tile ---------------
template<int KD, int QD>
__device__ __forceinline__ void dgemm_bf(
    const unsigned int* __restrict__ Bb, int Wb, int c0, int k0,
    const float* __restrict__ Q0r, const float* __restrict__ Q0i,
    const float2* __restrict__ Qrd, int s, int rg,
    unsigned int* sBu, float2 (*sQ)[8], float acc[8]) {
    const int tid = threadIdx.x;
    const int w = tid >> 6, lane = tid & 63;
    // stage step-invariant bf16 B slab (KD x 128)
    for (int slot = tid; slot < KD * 32; slot += 256) {
        int row = slot >> 5, cq = (slot & 31) << 2;
        *(uint4*)&sBu[(row << 7) + cq] = *(const uint4*)&Bb[(k0 + row) * Wb + c0 + cq];
    }
    // stage Q rows rg*8..+7 over [k0,k0+KD), resolving split-K partials (x4)
    constexpr int qsz = 128 * QD;
    for (int slot = tid; slot < 8 * KD; slot += 256) {
        int row = slot / KD, kk = slot - row * KD;
        int g = (rg * 8 + row) * QD + k0 + kk;
        float2 q;
        if (s == 0) {
            q = make_float2(Q0r[g], Q0i[g]);
        } else {
            float2 v0 = Qrd[g], v1 = Qrd[qsz + g];
            float2 v2 = Qrd[2 * qsz + g], v3 = Qrd[3 * qsz + g];
            q = make_float2(v0.x + v1.x + v2.x + v3.x, v0.y + v1.y + v2.y + v3.y);
        }
        sQ[kk][row] = q;
    }
    __syncthreads();
    cmul_inner<KD>(sBu, sQ, w, lane, acc);
}

// ---------------- dstep phase body (one block's task at step s) -------------
//  [0,192):   F:  QF*A2b. 48 tiles (16 rg x 3 cs) x 4 parts (KD 96)
//  [192,256): Ee: QF*BFb. 16 rg x 4 parts (KD 96); part0 subtracts QH[:,:128];
//             ALL Ee blocks resolve E_{s-1} -> Sm/S1 (init Sm at s=0)
//  [256,320): Eo1: QF*W1b -> Eo parts 0..3
//  [320,384): Eo2: -QH*Ab[:,:128] (KD 64) -> Eo parts 4..7
//  [384,512): H:  QH*AH2b. 32 tiles (16 rg x 2 cs) x 4 parts (KD 64)
__device__ __forceinline__ void dstep_body(const Params& P, int s, int b,
        unsigned int* sBu, float2 (*sQ)[8], float* red) {
    const int tid = threadIdx.x;
    const int w = tid >> 6, lane = tid & 63;

    const float2* QFrd = (s & 1) ? P.QFp1 : P.QFp0;
    float2*       QFwr = (s & 1) ? P.QFp0 : P.QFp1;
    const float2* QHrd = (s & 1) ? P.QHp1 : P.QHp0;
    float2*       QHwr = (s & 1) ? P.QHp0 : P.QHp1;
    const float2* Eerd = (s & 1) ? P.Eep1 : P.Eep0;
    float2*       Eewr = (s & 1) ? P.Eep0 : P.Eep1;
    const float2* Eord = (s & 1) ? P.Eop1 : P.Eop0;
    float2*       Eowr = (s & 1) ? P.Eop0 : P.Eop1;

    float acc[8] = {};

    if (b < 192) {                       // ---- F: QF*A2b
        int tile = b >> 2, part = b & 3;
        int rg = tile / 3, cs = tile - 3 * rg;
        dgemm_bf<96, 384>(P.A2b, 384, cs << 7, part * 96, P.CFr, P.CFi, QFrd, s, rg, sBu, sQ, acc);
        float2* O = QFwr + part * 49152;
        const int prow = rg * 8 + 2 * w, pcol = (cs << 7) + 2 * lane;
        *(float4*)&O[prow * 384 + pcol]       = make_float4(acc[0], acc[1], acc[2], acc[3]);
        *(float4*)&O[(prow + 1) * 384 + pcol] = make_float4(acc[4], acc[5], acc[6], acc[7]);
    } else if (b < 256) {                // ---- Ee: QF*BFb (+duties)
        int u = b - 192, rg = u >> 2, part = u & 3;
        if (s == 0) {
            int i = u * 256 + tid;
            P.Sm[i] = make_float2(P.DFr[i], P.DFi[i]);
        } else {
            int i = u * 256 + tid;
            float er = 0.f, ei = 0.f;
            #pragma unroll
            for (int pt = 0; pt < 4; ++pt) {
                float2 e = Eerd[pt * 16384 + i];
                er += e.x; ei += e.y;
            }
            #pragma unroll
            for (int pt = 0; pt < 8; ++pt) {
                float2 e = Eord[pt * 16384 + i];
                er += e.x; ei += e.y;
            }
            float2 sm = P.Sm[i];
            P.Sm[i] = make_float2(sm.x + er, sm.y + ei);
            float tot = block_reduce(er * er + ei * ei, red, tid);
            if (tid == 0) atomicAdd(P.S1, tot);
        }
        dgemm_bf<96, 384>(P.BFb, 128, 0, part * 96, P.CFr, P.CFi, QFrd, s, rg, sBu, sQ, acc);
        const int prow = rg * 8 + 2 * w, pcol = 2 * lane;
        if (part == 0) {   // subtract resolved QH[:, :128] exactly once
            if (s == 0) {
                acc[0] -= P.Cr[prow * 256 + pcol];           acc[1] -= P.Ci[prow * 256 + pcol];
                acc[2] -= P.Cr[prow * 256 + pcol + 1];       acc[3] -= P.Ci[prow * 256 + pcol + 1];
                acc[4] -= P.Cr[(prow + 1) * 256 + pcol];     acc[5] -= P.Ci[(prow + 1) * 256 + pcol];
                acc[6] -= P.Cr[(prow + 1) * 256 + pcol + 1]; acc[7] -= P.Ci[(prow + 1) * 256 + pcol + 1];
            } else {
                #pragma unroll
                for (int pt = 0; pt < 4; ++pt) {
                    const float2* qh = QHrd + pt * 32768;
                    float2 v0 = qh[prow * 256 + pcol], v1 = qh[prow * 256 + pcol + 1];
                    float2 u0 = qh[(prow + 1) * 256 + pcol], u1 = qh[(prow + 1) * 256 + pcol + 1];
                    acc[0] -= v0.x; acc[1] -= v0.y;  acc[2] -= v1.x; acc[3] -= v1.y;
                    acc[4] -= u0.x; acc[5] -= u0.y;  acc[6] -= u1.x; acc[7] -= u1.y;
                }
            }
        }
        float2* O = Eewr + part * 16384;
        *(float4*)&O[prow * 128 + pcol]       = make_float4(acc[0], acc[1], acc[2], acc[3]);
        *(float4*)&O[(prow + 1) * 128 + pcol] = make_float4(acc[4], acc[5], acc[6], acc[7]);
    } else if (b < 320) {                // ---- Eo1: QF*W1b
        int u = b - 256, rg = u >> 2, part = u & 3;
        dgemm_bf<96, 384>(P.W1b, 128, 0, part * 96, P.CFr, P.CFi, QFrd, s, rg, sBu, sQ, acc);
        float2* O = Eowr + part * 16384;
        const int prow = rg * 8 + 2 * w, pcol = 2 * lane;
        *(float4*)&O[prow * 128 + pcol]       = make_float4(acc[0], acc[1], acc[2], acc[3]);
        *(float4*)&O[(prow + 1) * 128 + pcol] = make_float4(acc[4], acc[5], acc[6], acc[7]);
    } else if (b < 384) {                // ---- Eo2: -QH*Ab[:, :128]
        int u = b - 320, rg = u >> 2, part = u & 3;
        dgemm_bf<64, 256>(P.Ab, 256, 0, part * 64, P.Cr, P.Ci, QHrd, s, rg, sBu, sQ, acc);
        float2* O = Eowr + (4 + part) * 16384;
        const int prow = rg * 8 + 2 * w, pcol = 2 * lane;
        *(float4*)&O[prow * 128 + pcol]       = make_float4(-acc[0], -acc[1], -acc[2], -acc[3]);
        *(float4*)&O[(prow + 1) * 128 + pcol] = make_float4(-acc[4], -acc[5], -acc[6], -acc[7]);
    } else {                             // ---- H: QH*AH2b
        int u = b - 384, tile = u >> 2, part = u & 3;
        int rg = tile >> 1, cs = tile & 1;
        dgemm_bf<64, 256>(P.AH2b, 256, cs << 7, part * 64, P.Cr, P.Ci, QHrd, s, rg, sBu, sQ, acc);
        float2* O = QHwr + part * 32768;
        const int prow = rg * 8 + 2 * w, pcol = (cs << 7) + 2 * lane;
        *(float4*)&O[prow * 256 + pcol]       = make_float4(acc[0], acc[1], acc[2], acc[3]);
        *(float4*)&O[(prow + 1) * 256 + pcol] = make_float4(acc[4], acc[5], acc[6], acc[7]);
    }
}

// =================== the single persistent kernel ===========================
// Grid 512 x 256, plain launch. 2 blocks/CU capacity -> all co-resident.
__global__ __launch_bounds__(256, 2)
void fused_kernel(Params P) {
    __shared__ __align__(16) unsigned int sBu[96 * 128];  // 48 KB
    __shared__ __align__(16) float2 sQ[96][8];            // 6 KB
    __shared__ float red[256];                            // 1 KB
    const int tid = threadIdx.x;
    const int w = tid >> 6, lane = tid & 63;

    // ---------------- phase 1: pre1 (1024 tasks, 2 per block) --------------
    //  [0,576):    A2 = AF*AF: 144 tiles (48 rg x 3 cs) x 4 parts (KD 96)
    //  [576,768):  W1 = AF*BF: 48 rg x 4 parts (KD 96)
    //  [768,1024): AH2 = A*A:  64 tiles (32 rg x 2 cs) x 4 parts (KD 64)
    for (int t = blockIdx.x; t < 1024; t += NBLK) {
        __syncthreads();   // protect LDS reuse across tasks
        int rg, c0 = 0, k0, Wq, Wb, Wo, part;
        const float *Qr_, *Qi_, *Br_, *Bi_;
        float2* O;
        bool kd96;
        if (t < 576) {
            int tile = t >> 2; part = t & 3; rg = tile / 3; int cs = tile - 3 * rg;
            c0 = cs << 7; k0 = part * 96; Wq = 384; Wb = 384; Wo = 384;
            Qr_ = P.AFr; Qi_ = P.AFi; Br_ = P.AFr; Bi_ = P.AFi; O = P.A2p + part * 147456;
            kd96 = true;
        } else if (t < 768) {
            int u = t - 576; rg = u >> 2; part = u & 3;
            k0 = part * 96; Wq = 384; Wb = 128; Wo = 128;
            Qr_ = P.AFr; Qi_ = P.AFi; Br_ = P.BFr; Bi_ = P.BFi; O = P.W1p + part * 49152;
            kd96 = true;
        } else {
            int u = t - 768; int tile = u >> 2; part = u & 3; rg = tile >> 1; int cs = tile & 1;
            c0 = cs << 7; k0 = part * 64; Wq = 256; Wb = 256; Wo = 256;
            Qr_ = P.Ar; Qi_ = P.Ai; Br_ = P.Ar; Bi_ = P.Ai; O = P.AH2p + part * 65536;
            kd96 = false;
        }
        float acc[8] = {};
        if (kd96) pre1_body<96>(Qr_, Qi_, Br_, Bi_, Wq, Wb, rg, c0, k0, sBu, sQ, w, lane, acc);
        else      pre1_body<64>(Qr_, Qi_, Br_, Bi_, Wq, Wb, rg, c0, k0, sBu, sQ, w, lane, acc);
        const int prow = rg * 8 + 2 * w, pcol = c0 + 2 * lane;
        *(float4*)&O[prow * Wo + pcol]       = make_float4(acc[0], acc[1], acc[2], acc[3]);
        *(float4*)&O[(prow + 1) * Wo + pcol] = make_float4(acc[4], acc[5], acc[6], acc[7]);
    }
    grid_barrier(P.bcnt, P.bgen);

    // ---------------- phase 2: pre2 (resolve partials -> bf16) -------------
    for (int idx = (int)blockIdx.x * 256 + tid; idx < 376832; idx += NBLK * 256) {
        if (idx < 147456) {
            float2 a = P.A2p[idx], b2 = P.A2p[147456 + idx];
            float2 c = P.A2p[294912 + idx], d = P.A2p[442368 + idx];
            P.A2b[idx] = f2bf2(a.x + b2.x + c.x + d.x, a.y + b2.y + c.y + d.y);
        } else if (idx < 196608) {
            int j = idx - 147456;
            float2 a = P.W1p[j], b2 = P.W1p[49152 + j];
            float2 c = P.W1p[98304 + j], d = P.W1p[147456 + j];
            P.W1b[j] = f2bf2(a.x + b2.x + c.x + d.x, a.y + b2.y + c.y + d.y);
        } else if (idx < 262144) {
            int j = idx - 196608;
            float2 a = P.AH2p[j], b2 = P.AH2p[65536 + j];
            float2 c = P.AH2p[131072 + j], d = P.AH2p[196608 + j];
            P.AH2b[j] = f2bf2(a.x + b2.x + c.x + d.x, a.y + b2.y + c.y + d.y);
        } else if (idx < 311296) {
            int j = idx - 262144;
            P.BFb[j] = f2bf2(P.BFr[j], P.BFi[j]);
        } else {
            int j = idx - 311296;
            P.Ab[j] = f2bf2(P.Ar[j], P.Ai[j]);
        }
    }
    grid_barrier(P.bcnt, P.bgen);

    // ---------------- phase 3: KSTEPS double-steps -------------------------
    for (int s = 0; s < KSTEPS; ++s) {
        const int b = blockIdx.x;
        // last step: only E-sections (QF/QH advance would be dead work)
        if (s < KSTEPS - 1 || (b >= 192 && b < 384))
            dstep_body(P, s, b, sBu, sQ, red);
        grid_barrier(P.bcnt, P.bgen);
    }

    // ---------------- phase 4: finalize + ticketed scalar out --------------
    if (blockIdx.x < 64) {
        const float2* Ee = ((KSTEPS - 1) & 1) ? P.Eep0 : P.Eep1;
        const float2* Eo = ((KSTEPS - 1) & 1) ? P.Eop0 : P.Eop1;
        int i = ((int)blockIdx.x << 8) + tid;
        float er = 0.f, ei = 0.f;
        #pragma unroll
        for (int pt = 0; pt < 4; ++pt) { float2 e = Ee[pt * 16384 + i]; er += e.x; ei += e.y; }
        #pragma unroll
        for (int pt = 0; pt < 8; ++pt) { float2 e = Eo[pt * 16384 + i]; er += e.x; ei += e.y; }
        float2 sm = P.Sm[i];
        float smr = sm.x + er, smi = sm.y + ei;
        float dr = P.DFr[i], di = P.DFi[i];
        float t1 = block_reduce(er * er + ei * ei, red, tid);
        if (tid == 0) atomicAdd(P.S1, t1);
        float t2 = block_reduce(smr * smr + smi * smi, red, tid);
        if (tid == 0) atomicAdd(P.S2, t2);
        float t3 = block_reduce(dr * dr + di * di, red, tid);
        if (tid == 0) atomicAdd(P.SD, t3);
        if (tid == 0) {
            __threadfence();
            unsigned int t = atomicAdd(P.tick, 1u);
            if (t == 63u) {
                __threadfence();
                float s1 = atomicAdd(P.S1, 0.f);
                float s2 = atomicAdd(P.S2, 0.f);
                float sd = atomicAdd(P.SD, 0.f);
                P.out[0] = (99.0f * (s1 + sd) + s2) / 100.0f;
            }
        }
    }
}

extern "C" void kernel_launch(void* const* d_in, const int* in_sizes, int n_in,
                              void* d_out, int out_size, void* d_ws, size_t ws_size,
                              hipStream_t stream) {
    (void)in_sizes; (void)n_in; (void)out_size; (void)ws_size;
    char* ws = (char*)d_ws;
    Params h;
    h.Cr  = (const float*)d_in[0];
    h.Ci  = (const float*)d_in[1];
    h.Ar  = (const float*)d_in[2];
    h.Ai  = (const float*)d_in[3];
    h.AFr = (const float*)d_in[4];
    h.AFi = (const float*)d_in[5];
    h.BFr = (const float*)d_in[6];
    h.BFi = (const float*)d_in[7];
    h.CFr = (const float*)d_in[8];
    h.CFi = (const float*)d_in[9];
    h.DFr = (const float*)d_in[10];
    h.DFi = (const float*)d_in[11];
    h.A2p  = (float2*)(ws + 0);                 // 4*147456*8 = 4718592
    h.W1p  = (float2*)(ws + 4718592);           // 4*49152*8  = 1572864
    h.AH2p = (float2*)(ws + 6291456);           // 4*65536*8  = 2097152
    h.A2b  = (unsigned int*)(ws + 8388608);     // 147456*4 = 589824
    h.W1b  = (unsigned int*)(ws + 8978432);     // 196608
    h.AH2b = (unsigned int*)(ws + 9175040);     // 262144
    h.BFb  = (unsigned int*)(ws + 9437184);     // 196608
    h.Ab   = (unsigned int*)(ws + 9633792);     // 262144
    h.QFp0 = (float2*)(ws + 9895936);           // 4*49152*8 = 1572864
    h.QFp1 = (float2*)(ws + 11468800);
    h.QHp0 = (float2*)(ws + 13041664);          // 4*32768*8 = 1048576
    h.QHp1 = (float2*)(ws + 14090240);
    h.Eep0 = (float2*)(ws + 15138816);          // 4*16384*8 = 524288
    h.Eep1 = (float2*)(ws + 15663104);
    h.Eop0 = (float2*)(ws + 16187392);          // 8*16384*8 = 1048576
    h.Eop1 = (float2*)(ws + 17235968);
    h.Sm   = (float2*)(ws + 18284544);          // 131072
    h.S1   = (float*)(ws + 18415616);
    h.S2   = (float*)(ws + 18415620);
    h.SD   = (float*)(ws + 18415624);
    h.tick = (unsigned int*)(ws + 18415628);
    h.bcnt = (unsigned int*)(ws + 18415632);
    h.bgen = (unsigned int*)(ws + 18415636);
    h.out  = (float*)d_out;

    // zero S1,S2,SD,tick,bcnt,bgen (workspace is re-poisoned each iteration)
    hipMemsetAsync(ws + 18415616, 0, 24, stream);
    hipLaunchKernelGGL(fused_kernel, dim3(NBLK), dim3(256), 0, stream, h);
}

// Round 4
// 313.307 us; speedup vs baseline: 1.5862x; 1.5862x over previous
//
#include <hip/hip_runtime.h>

// obj = (99*sum_t ||c_t||^2 + ||sum_t c_t||^2)/100 (Parseval over the 100
// samples = 99th roots of unity, z=1 double-counted), c_0 = D_F,
// c_{k+1} = E_k = C_F A_F^k B_F - C A^k B, B = eye(256,128).
// DOUBLE-STEP with bf16 constant matrices:
//   pre1: split-K partials of A2=AF^2, W1=AF*BF, AH2=A^2 (fp32 acc, bf16 B)
//   pre2: resolve partials; convert A2,W1,AH2,BF,A to packed bf16 (r|i<<16)
//   dstep s: Ee_s = QF*BFb - QH[:,:128]; Eo_s = QF*W1b - QH*Ab[:,:128];
//            QF <- QF*A2b; QH <- QH*AH2b   (Q fp32, B-slabs bf16)
// Persistent single kernel. Round-3 post-mortem: __threadfence_system() per
// block-leader per barrier = ~6100 serialized L2-writeback walks ~= 390 us.
// This revision: NO cache flushes at all. All cross-phase shared data moves
// via system-scope relaxed atomics (sc0 sc1 -> write-through/read-through the
// die-level LLC, which IS coherent across XCDs). Write-once bf16 tables are
// system-stored before the barrier and first-read after it, so cached uint4
// staging loads stay legal. Grid barrier = s_waitcnt vmcnt(0) + one packed
// 64-bit {count|gen} fetch_add + load-spin (race-free, no fences).

#define KSTEPS 4   // double-steps -> E_0..E_7
#define NBLK 512

struct Params {
    const float *AFr, *AFi, *Ar, *Ai, *BFr, *BFi, *CFr, *CFi, *Cr, *Ci, *DFr, *DFi;
    float2 *A2p, *W1p, *AH2p;                 // pre1 split-K partials (x4)
    unsigned int *A2b, *W1b, *AH2b, *BFb, *Ab;  // packed bf16 constants
    float2 *QFp0, *QFp1, *QHp0, *QHp1, *Eep0, *Eep1, *Eop0, *Eop1, *Sm;
    float *S1, *S2, *SD, *out;
    unsigned int *tick;
    unsigned long long *bar;                  // packed {gen:32 | count:32}
};

__device__ __forceinline__ unsigned int f2bf2(float r, float i) {
    unsigned int ur = __float_as_uint(r); ur = (ur + 0x7fffu + ((ur >> 16) & 1u)) >> 16;
    unsigned int ui = __float_as_uint(i); ui = (ui + 0x7fffu + ((ui >> 16) & 1u)) >> 16;
    return ur | (ui << 16);
}

// ---- system-scope (LLC coherence point) 8B load/store: bypass L1+L2 -------
__device__ __forceinline__ float2 ld_sys(const float2* p) {
    unsigned long long v = __hip_atomic_load((const unsigned long long*)p,
                                 __ATOMIC_RELAXED, __HIP_MEMORY_SCOPE_SYSTEM);
    union { unsigned long long u; float2 f; } c; c.u = v; return c.f;
}
__device__ __forceinline__ void st_sys(float2* p, float2 v) {
    union { float2 f; unsigned long long u; } c; c.f = v;
    __hip_atomic_store((unsigned long long*)p, c.u,
                       __ATOMIC_RELAXED, __HIP_MEMORY_SCOPE_SYSTEM);
}
__device__ __forceinline__ void st_sys_u32(unsigned int* p, unsigned int v) {
    __hip_atomic_store(p, v, __ATOMIC_RELAXED, __HIP_MEMORY_SCOPE_SYSTEM);
}

// Packed-word grid barrier: low32 = arrival count, high32 = generation.
// No cache maintenance: all shared data is already at the LLC (system-scope
// stores), so completion (vmcnt(0)) + one RMW is a full release; readers use
// system-scope loads, so no invalidate is needed on the acquire side.
__device__ __forceinline__ void grid_barrier(unsigned long long* bar) {
    __syncthreads();
    if (threadIdx.x == 0) {
        asm volatile("s_waitcnt vmcnt(0)" ::: "memory");
        unsigned long long old = __hip_atomic_fetch_add(bar, 1ull,
                                     __ATOMIC_RELAXED, __HIP_MEMORY_SCOPE_AGENT);
        unsigned int g = (unsigned int)(old >> 32);
        if ((unsigned int)old == NBLK - 1u) {
            // last arriver: zero count, bump generation (single atomic)
            __hip_atomic_fetch_add(bar, (1ull << 32) - (unsigned long long)NBLK,
                                   __ATOMIC_RELAXED, __HIP_MEMORY_SCOPE_AGENT);
        } else {
            while ((unsigned int)(__hip_atomic_load(bar, __ATOMIC_RELAXED,
                        __HIP_MEMORY_SCOPE_SYSTEM) >> 32) == g)
                __builtin_amdgcn_s_sleep(2);
        }
        asm volatile("" ::: "memory");
    }
    __syncthreads();
}

__device__ __forceinline__ float block_reduce(float v, float* red, int tid) {
    red[tid] = v;
    __syncthreads();
    for (int off = 128; off > 0; off >>= 1) {
        if (tid < off) red[tid] += red[tid + off];
        __syncthreads();
    }
    float r = red[0];
    __syncthreads();
    return r;
}

// Barrier-free complex inner product: Q (fp32, LDS broadcast rows) x
// B (bf16-packed, LDS persistent slab), 2x2 output tile per thread.
template<int KD>
__device__ __forceinline__ void cmul_inner(const unsigned int* __restrict__ sBu,
                                           const float2 (*__restrict__ sQ)[8],
                                           int w, int lane, float acc[8]) {
    #pragma unroll 8
    for (int kk = 0; kk < KD; ++kk) {
        float4 qv = *(const float4*)&sQ[kk][2 * w];
        uint2 bu = *(const uint2*)&sBu[(kk << 7) + 2 * lane];
        float b0r = __uint_as_float(bu.x << 16);
        float b0i = __uint_as_float(bu.x & 0xffff0000u);
        float b1r = __uint_as_float(bu.y << 16);
        float b1i = __uint_as_float(bu.y & 0xffff0000u);
        acc[0] += qv.x * b0r - qv.y * b0i;  acc[1] += qv.x * b0i + qv.y * b0r;
        acc[2] += qv.x * b1r - qv.y * b1i;  acc[3] += qv.x * b1i + qv.y * b1r;
        acc[4] += qv.z * b0r - qv.w * b0i;  acc[5] += qv.z * b0i + qv.w * b0r;
        acc[6] += qv.z * b1r - qv.w * b1i;  acc[7] += qv.z * b1i + qv.w * b1r;
    }
}

// ---------------- pre1 task body: one split-K partial tile ------------------
template<int KD>
__device__ __forceinline__ void pre1_body(const float* __restrict__ Qr_,
        const float* __restrict__ Qi_, const float* __restrict__ Br_,
        const float* __restrict__ Bi_, int Wq, int Wb, int rg, int c0, int k0,
        unsigned int* sBu, float2 (*sQ)[8], int w, int lane, float acc[8]) {
    const int tid = threadIdx.x;
    // stage whole B slab, converting fp32 pairs -> packed bf16 on the fly
    for (int slot = tid; slot < KD * 32; slot += 256) {
        int row = slot >> 5, cq = (slot & 31) << 2;
        int g = (k0 + row) * Wb + c0 + cq;
        float4 vr = *(const float4*)&Br_[g];
        float4 vi = *(const float4*)&Bi_[g];
        *(uint4*)&sBu[(row << 7) + cq] = make_uint4(
            f2bf2(vr.x, vi.x), f2bf2(vr.y, vi.y), f2bf2(vr.z, vi.z), f2bf2(vr.w, vi.w));
    }
    // stage Q rows rg*8..+7 over [k0,k0+KD)  (inputs: plain cached loads)
    for (int slot = tid; slot < 8 * KD; slot += 256) {
        int row = slot / KD, kk = slot - row * KD;
        int g = (rg * 8 + row) * Wq + k0 + kk;
        sQ[kk][row] = make_float2(Qr_[g], Qi_[g]);
    }
    __syncthreads();
    cmul_inner<KD>(sBu, sQ, w, lane, acc);
}

// ---------------- double-step GEMM: fp32 Q x bf16 B, 2x2 tile ---------------
template<int KD, int QD>
__device__ __forceinline__ void dgemm_bf(
    const unsigned int* __restrict__ Bb, int Wb, int c0, int k0,
    const float* __restrict__ Q0r, const float* __restrict__ Q0i,
    const float2* __restrict__ Qrd, int s, int rg,
    unsigned int* sBu, float2 (*sQ)[8], float acc[8]) {
    const int tid = threadIdx.x;
    const int w = tid >> 6, lane = tid & 63;
    // stage step-invariant bf16 B slab (KD x 128) — tables are write-once
    // (system-stored in pre2 phase, first-read here) so cached loads are safe
    for (int slot = tid; slot < KD * 32; slot += 256) {
        int row = slot >> 5, cq = (slot & 31) << 2;
        *(uint4*)&sBu[(row << 7) + cq] = *(const uint4*)&Bb[(k0 + row) * Wb + c0 + cq];
    }
    // stage Q rows rg*8..+7 over [k0,k0+KD), resolving split-K partials (x4)
    constexpr int qsz = 128 * QD;
    for (int slot = tid; slot < 8 * KD; slot += 256) {
        int row = slot / KD, kk = slot - row * KD;
        int g = (rg * 8 + row) * QD + k0 + kk;
        float2 q;
        if (s == 0) {
            q = make_float2(Q0r[g], Q0i[g]);     // inputs: cached
        } else {
            float2 v0 = ld_sys(Qrd + g),           v1 = ld_sys(Qrd + qsz + g);
            float2 v2 = ld_sys(Qrd + 2 * qsz + g), v3 = ld_sys(Qrd + 3 * qsz + g);
            q = make_float2(v0.x + v1.x + v2.x + v3.x, v0.y + v1.y + v2.y + v3.y);
        }
        sQ[kk][row] = q;
    }
    __syncthreads();
    cmul_inner<KD>(sBu, sQ, w, lane, acc);
}

// store a 2x2 complex tile (two float4-equivalents) through to the LLC
__device__ __forceinline__ void st_tile(float2* O, int W, int prow, int pcol,
                                        const float acc[8], float sgn) {
    st_sys(&O[prow * W + pcol],           make_float2(sgn * acc[0], sgn * acc[1]));
    st_sys(&O[prow * W + pcol + 1],       make_float2(sgn * acc[2], sgn * acc[3]));
    st_sys(&O[(prow + 1) * W + pcol],     make_float2(sgn * acc[4], sgn * acc[5]));
    st_sys(&O[(prow + 1) * W + pcol + 1], make_float2(sgn * acc[6], sgn * acc[7]));
}

// ---------------- dstep phase body (one block's task at step s) -------------
//  [0,192):   F:  QF*A2b. 48 tiles (16 rg x 3 cs) x 4 parts (KD 96)
//  [192,256): Ee: QF*BFb. 16 rg x 4 parts (KD 96); part0 subtracts QH[:,:128];
//             ALL Ee blocks resolve E_{s-1} -> Sm/S1 (init Sm at s=0)
//  [256,320): Eo1: QF*W1b -> Eo parts 0..3
//  [320,384): Eo2: -QH*Ab[:,:128] (KD 64) -> Eo parts 4..7
//  [384,512): H:  QH*AH2b. 32 tiles (16 rg x 2 cs) x 4 parts (KD 64)
__device__ __forceinline__ void dstep_body(const Params& P, int s, int b,
        unsigned int* sBu, float2 (*sQ)[8], float* red) {
    const int tid = threadIdx.x;
    const int w = tid >> 6, lane = tid & 63;

    const float2* QFrd = (s & 1) ? P.QFp1 : P.QFp0;
    float2*       QFwr = (s & 1) ? P.QFp0 : P.QFp1;
    const float2* QHrd = (s & 1) ? P.QHp1 : P.QHp0;
    float2*       QHwr = (s & 1) ? P.QHp0 : P.QHp1;
    const float2* Eerd = (s & 1) ? P.Eep1 : P.Eep0;
    float2*       Eewr = (s & 1) ? P.Eep0 : P.Eep1;
    const float2* Eord = (s & 1) ? P.Eop1 : P.Eop0;
    float2*       Eowr = (s & 1) ? P.Eop0 : P.Eop1;

    float acc[8] = {};

    if (b < 192) {                       // ---- F: QF*A2b
        int tile = b >> 2, part = b & 3;
        int rg = tile / 3, cs = tile - 3 * rg;
        dgemm_bf<96, 384>(P.A2b, 384, cs << 7, part * 96, P.CFr, P.CFi, QFrd, s, rg, sBu, sQ, acc);
        const int prow = rg * 8 + 2 * w, pcol = (cs << 7) + 2 * lane;
        st_tile(QFwr + part * 49152, 384, prow, pcol, acc, 1.f);
    } else if (b < 256) {                // ---- Ee: QF*BFb (+duties)
        int u = b - 192, rg = u >> 2, part = u & 3;
        if (s == 0) {
            int i = u * 256 + tid;
            st_sys(&P.Sm[i], make_float2(P.DFr[i], P.DFi[i]));
        } else {
            int i = u * 256 + tid;
            float er = 0.f, ei = 0.f;
            #pragma unroll
            for (int pt = 0; pt < 4; ++pt) {
                float2 e = ld_sys(Eerd + pt * 16384 + i);
                er += e.x; ei += e.y;
            }
            #pragma unroll
            for (int pt = 0; pt < 8; ++pt) {
                float2 e = ld_sys(Eord + pt * 16384 + i);
                er += e.x; ei += e.y;
            }
            float2 sm = ld_sys(&P.Sm[i]);
            st_sys(&P.Sm[i], make_float2(sm.x + er, sm.y + ei));
            float tot = block_reduce(er * er + ei * ei, red, tid);
            if (tid == 0) atomicAdd(P.S1, tot);
        }
        dgemm_bf<96, 384>(P.BFb, 128, 0, part * 96, P.CFr, P.CFi, QFrd, s, rg, sBu, sQ, acc);
        const int prow = rg * 8 + 2 * w, pcol = 2 * lane;
        if (part == 0) {   // subtract resolved QH[:, :128] exactly once
            if (s == 0) {
                acc[0] -= P.Cr[prow * 256 + pcol];           acc[1] -= P.Ci[prow * 256 + pcol];
                acc[2] -= P.Cr[prow * 256 + pcol + 1];       acc[3] -= P.Ci[prow * 256 + pcol + 1];
                acc[4] -= P.Cr[(prow + 1) * 256 + pcol];     acc[5] -= P.Ci[(prow + 1) * 256 + pcol];
                acc[6] -= P.Cr[(prow + 1) * 256 + pcol + 1]; acc[7] -= P.Ci[(prow + 1) * 256 + pcol + 1];
            } else {
                #pragma unroll
                for (int pt = 0; pt < 4; ++pt) {
                    const float2* qh = QHrd + pt * 32768;
                    float2 v0 = ld_sys(qh + prow * 256 + pcol);
                    float2 v1 = ld_sys(qh + prow * 256 + pcol + 1);
                    float2 u0 = ld_sys(qh + (prow + 1) * 256 + pcol);
                    float2 u1 = ld_sys(qh + (prow + 1) * 256 + pcol + 1);
                    acc[0] -= v0.x; acc[1] -= v0.y;  acc[2] -= v1.x; acc[3] -= v1.y;
                    acc[4] -= u0.x; acc[5] -= u0.y;  acc[6] -= u1.x; acc[7] -= u1.y;
                }
            }
        }
        st_tile(Eewr + part * 16384, 128, prow, pcol, acc, 1.f);
    } else if (b < 320) {                // ---- Eo1: QF*W1b
        int u = b - 256, rg = u >> 2, part = u & 3;
        dgemm_bf<96, 384>(P.W1b, 128, 0, part * 96, P.CFr, P.CFi, QFrd, s, rg, sBu, sQ, acc);
        const int prow = rg * 8 + 2 * w, pcol = 2 * lane;
        st_tile(Eowr + part * 16384, 128, prow, pcol, acc, 1.f);
    } else if (b < 384) {                // ---- Eo2: -QH*Ab[:, :128]
        int u = b - 320, rg = u >> 2, part = u & 3;
        dgemm_bf<64, 256>(P.Ab, 256, 0, part * 64, P.Cr, P.Ci, QHrd, s, rg, sBu, sQ, acc);
        const int prow = rg * 8 + 2 * w, pcol = 2 * lane;
        st_tile(Eowr + (4 + part) * 16384, 128, prow, pcol, acc, -1.f);
    } else {                             // ---- H: QH*AH2b
        int u = b - 384, tile = u >> 2, part = u & 3;
        int rg = tile >> 1, cs = tile & 1;
        dgemm_bf<64, 256>(P.AH2b, 256, cs << 7, part * 64, P.Cr, P.Ci, QHrd, s, rg, sBu, sQ, acc);
        const int prow = rg * 8 + 2 * w, pcol = (cs << 7) + 2 * lane;
        st_tile(QHwr + part * 32768, 256, prow, pcol, acc, 1.f);
    }
}

// =================== the single persistent kernel ===========================
// Grid 512 x 256, plain launch. 2 blocks/CU capacity -> all co-resident.
__global__ __launch_bounds__(256, 2)
void fused_kernel(Params P) {
    __shared__ __align__(16) unsigned int sBu[96 * 128];  // 48 KB
    __shared__ __align__(16) float2 sQ[96][8];            // 6 KB
    __shared__ float red[256];                            // 1 KB
    const int tid = threadIdx.x;
    const int w = tid >> 6, lane = tid & 63;

    // ---------------- phase 1: pre1 (1024 tasks, 2 per block) --------------
    //  [0,576):    A2 = AF*AF: 144 tiles (48 rg x 3 cs) x 4 parts (KD 96)
    //  [576,768):  W1 = AF*BF: 48 rg x 4 parts (KD 96)
    //  [768,1024): AH2 = A*A:  64 tiles (32 rg x 2 cs) x 4 parts (KD 64)
    for (int t = blockIdx.x; t < 1024; t += NBLK) {
        __syncthreads();   // protect LDS reuse across tasks
        int rg, c0 = 0, k0, Wq, Wb, Wo, part;
        const float *Qr_, *Qi_, *Br_, *Bi_;
        float2* O;
        bool kd96;
        if (t < 576) {
            int tile = t >> 2; part = t & 3; rg = tile / 3; int cs = tile - 3 * rg;
            c0 = cs << 7; k0 = part * 96; Wq = 384; Wb = 384; Wo = 384;
            Qr_ = P.AFr; Qi_ = P.AFi; Br_ = P.AFr; Bi_ = P.AFi; O = P.A2p + part * 147456;
            kd96 = true;
        } else if (t < 768) {
            int u = t - 576; rg = u >> 2; part = u & 3;
            k0 = part * 96; Wq = 384; Wb = 128; Wo = 128;
            Qr_ = P.AFr; Qi_ = P.AFi; Br_ = P.BFr; Bi_ = P.BFi; O = P.W1p + part * 49152;
            kd96 = true;
        } else {
            int u = t - 768; int tile = u >> 2; part = u & 3; rg = tile >> 1; int cs = tile & 1;
            c0 = cs << 7; k0 = part * 64; Wq = 256; Wb = 256; Wo = 256;
            Qr_ = P.Ar; Qi_ = P.Ai; Br_ = P.Ar; Bi_ = P.Ai; O = P.AH2p + part * 65536;
            kd96 = false;
        }
        float acc[8] = {};
        if (kd96) pre1_body<96>(Qr_, Qi_, Br_, Bi_, Wq, Wb, rg, c0, k0, sBu, sQ, w, lane, acc);
        else      pre1_body<64>(Qr_, Qi_, Br_, Bi_, Wq, Wb, rg, c0, k0, sBu, sQ, w, lane, acc);
        const int prow = rg * 8 + 2 * w, pcol = c0 + 2 * lane;
        st_tile(O, Wo, prow, pcol, acc, 1.f);
    }
    grid_barrier(P.bar);

    // ---------------- phase 2: pre2 (resolve partials -> bf16 tables) ------
    for (int idx = (int)blockIdx.x * 256 + tid; idx < 376832; idx += NBLK * 256) {
        if (idx < 147456) {
            float2 a = ld_sys(P.A2p + idx),          b2 = ld_sys(P.A2p + 147456 + idx);
            float2 c = ld_sys(P.A2p + 294912 + idx), d  = ld_sys(P.A2p + 442368 + idx);
            st_sys_u32(&P.A2b[idx], f2bf2(a.x + b2.x + c.x + d.x, a.y + b2.y + c.y + d.y));
        } else if (idx < 196608) {
            int j = idx - 147456;
            float2 a = ld_sys(P.W1p + j),           b2 = ld_sys(P.W1p + 49152 + j);
            float2 c = ld_sys(P.W1p + 98304 + j),   d  = ld_sys(P.W1p + 147456 + j);
            st_sys_u32(&P.W1b[j], f2bf2(a.x + b2.x + c.x + d.x, a.y + b2.y + c.y + d.y));
        } else if (idx < 262144) {
            int j = idx - 196608;
            float2 a = ld_sys(P.AH2p + j),          b2 = ld_sys(P.AH2p + 65536 + j);
            float2 c = ld_sys(P.AH2p + 131072 + j), d  = ld_sys(P.AH2p + 196608 + j);
            st_sys_u32(&P.AH2b[j], f2bf2(a.x + b2.x + c.x + d.x, a.y + b2.y + c.y + d.y));
        } else if (idx < 311296) {
            int j = idx - 262144;
            st_sys_u32(&P.BFb[j], f2bf2(P.BFr[j], P.BFi[j]));
        } else {
            int j = idx - 311296;
            st_sys_u32(&P.Ab[j], f2bf2(P.Ar[j], P.Ai[j]));
        }
    }
    grid_barrier(P.bar);

    // ---------------- phase 3: KSTEPS double-steps -------------------------
    for (int s = 0; s < KSTEPS; ++s) {
        const int b = blockIdx.x;
        // last step: only E-sections (QF/QH advance would be dead work)
        if (s < KSTEPS - 1 || (b >= 192 && b < 384))
            dstep_body(P, s, b, sBu, sQ, red);
        grid_barrier(P.bar);
    }

    // ---------------- phase 4: finalize + ticketed scalar out --------------
    if (blockIdx.x < 64) {
        const float2* Ee = ((KSTEPS - 1) & 1) ? P.Eep0 : P.Eep1;
        const float2* Eo = ((KSTEPS - 1) & 1) ? P.Eop0 : P.Eop1;
        int i = ((int)blockIdx.x << 8) + tid;
        float er = 0.f, ei = 0.f;
        #pragma unroll
        for (int pt = 0; pt < 4; ++pt) { float2 e = ld_sys(Ee + pt * 16384 + i); er += e.x; ei += e.y; }
        #pragma unroll
        for (int pt = 0; pt < 8; ++pt) { float2 e = ld_sys(Eo + pt * 16384 + i); er += e.x; ei += e.y; }
        float2 sm = ld_sys(&P.Sm[i]);
        float smr = sm.x + er, smi = sm.y + ei;
        float dr = P.DFr[i], di = P.DFi[i];
        float t1 = block_reduce(er * er + ei * ei, red, tid);
        if (tid == 0) atomicAdd(P.S1, t1);
        float t2 = block_reduce(smr * smr + smi * smi, red, tid);
        if (tid == 0) atomicAdd(P.S2, t2);
        float t3 = block_reduce(dr * dr + di * di, red, tid);
        if (tid == 0) atomicAdd(P.SD, t3);
        if (tid == 0) {
            // order S1/S2/SD adds (LLC RMWs) before the ticket add
            asm volatile("s_waitcnt vmcnt(0)" ::: "memory");
            unsigned int t = atomicAdd(P.tick, 1u);
            if (t == 63u) {
                float s1 = atomicAdd(P.S1, 0.f);
                float s2 = atomicAdd(P.S2, 0.f);
                float sd = atomicAdd(P.SD, 0.f);
                P.out[0] = (99.0f * (s1 + sd) + s2) / 100.0f;
            }
        }
    }
}

extern "C" void kernel_launch(void* const* d_in, const int* in_sizes, int n_in,
                              void* d_out, int out_size, void* d_ws, size_t ws_size,
                              hipStream_t stream) {
    (void)in_sizes; (void)n_in; (void)out_size; (void)ws_size;
    char* ws = (char*)d_ws;
    Params h;
    h.Cr  = (const float*)d_in[0];
    h.Ci  = (const float*)d_in[1];
    h.Ar  = (const float*)d_in[2];
    h.Ai  = (const float*)d_in[3];
    h.AFr = (const float*)d_in[4];
    h.AFi = (const float*)d_in[5];
    h.BFr = (const float*)d_in[6];
    h.BFi = (const float*)d_in[7];
    h.CFr = (const float*)d_in[8];
    h.CFi = (const float*)d_in[9];
    h.DFr = (const float*)d_in[10];
    h.DFi = (const float*)d_in[11];
    h.A2p  = (float2*)(ws + 0);                 // 4*147456*8 = 4718592
    h.W1p  = (float2*)(ws + 4718592);           // 4*49152*8  = 1572864
    h.AH2p = (float2*)(ws + 6291456);           // 4*65536*8  = 2097152
    h.A2b  = (unsigned int*)(ws + 8388608);     // 147456*4 = 589824
    h.W1b  = (unsigned int*)(ws + 8978432);     // 196608
    h.AH2b = (unsigned int*)(ws + 9175040);     // 262144
    h.BFb  = (unsigned int*)(ws + 9437184);     // 196608
    h.Ab   = (unsigned int*)(ws + 9633792);     // 262144
    h.QFp0 = (float2*)(ws + 9895936);           // 4*49152*8 = 1572864
    h.QFp1 = (float2*)(ws + 11468800);
    h.QHp0 = (float2*)(ws + 13041664);          // 4*32768*8 = 1048576
    h.QHp1 = (float2*)(ws + 14090240);
    h.Eep0 = (float2*)(ws + 15138816);          // 4*16384*8 = 524288
    h.Eep1 = (float2*)(ws + 15663104);
    h.Eop0 = (float2*)(ws + 16187392);          // 8*16384*8 = 1048576
    h.Eop1 = (float2*)(ws + 17235968);
    h.Sm   = (float2*)(ws + 18284544);          // 131072
    h.S1   = (float*)(ws + 18415616);
    h.S2   = (float*)(ws + 18415620);
    h.SD   = (float*)(ws + 18415624);
    h.tick = (unsigned int*)(ws + 18415628);
    h.bar  = (unsigned long long*)(ws + 18415632);  // 8B, 8-aligned
    h.out  = (float*)d_out;

    // zero S1,S2,SD,tick,bar (workspace is re-poisoned each iteration)
    hipMemsetAsync(ws + 18415616, 0, 24, stream);
    hipLaunchKernelGGL(fused_kernel, dim3(NBLK), dim3(256), 0, stream, h);
}

// Round 5
// 260.300 us; speedup vs baseline: 1.9092x; 1.2036x over previous
//
#include <hip/hip_runtime.h>

// obj = (99*sum_t ||c_t||^2 + ||sum_t c_t||^2)/100 (Parseval over the 100
// samples = 99th roots of unity, z=1 double-counted), c_0 = D_F,
// c_{k+1} = E_k = C_F A_F^k B_F - C A^k B, B = eye(256,128), k=0..7
// (K=8 truncation verified earlier: tail ~1e3 << 1e6 threshold).
//
// POWER-DOUBLING restructure (this round): instead of 4 serial double-steps,
// build G_k = C_F A_F^k and H_k = C A^k for k=0..7 by log-doubling with row
// stacking -> serial chain of 4 kernels (was 7):
//   P1: AF2=AF*AF, G1=CF*AF, A2=A*A, H1=C*A   (+ copies G0=CF,H0=C,Sm=DF)
//   P2: AF4b=bf16(AF2*AF2b), [G2;G3]=[G0;G1]*AF2b, A4b, [H2;H3]
//   P3: [G4..G7]=[G0..G3]*AF4b, [H4..H7]=[H0..H3]*A4b
//   P4: E=[G0..G7]*BFb - H[:,:128]; S1+=|E|^2; Sm+=E (atomics); ticketed
//       last block reduces S2=|Sm|^2, SD=|DF|^2 and writes the scalar.
// Full-K per block (K=384/256 chunked 128 rows through LDS) -> no split-K,
// no resolve phase; each GEMM epilogue writes fp32 and/or packed-bf16
// (r | i<<16) directly. B operands consumed as bf16 (converted on the fly
// from fp32 inputs, or read from the bf16 product tables); Q rows and all
// accumulation stay fp32 — same numerics class as the passing round-1 kernel.
// Round-3/4 lesson: in-kernel grid barriers (fences or LLC spin) cost far
// more than kernel-boundary flushes; so these are 4 plain launches.

struct Params {
    const float *AFr, *AFi, *Ar, *Ai, *BFr, *BFi, *CFr, *CFi, *Cr, *Ci, *DFr, *DFi;
    float2 *Gf, *Hf, *AF2f, *A2f, *Sm;          // fp32 complex buffers
    unsigned int *AF2b, *AF4b, *A2b, *A4b;      // packed bf16 tables
    float *S1; unsigned int *tick; float *out;
};

__device__ __forceinline__ unsigned int f2bf2(float r, float i) {
    unsigned int ur = __float_as_uint(r); ur = (ur + 0x7fffu + ((ur >> 16) & 1u)) >> 16;
    unsigned int ui = __float_as_uint(i); ui = (ui + 0x7fffu + ((ui >> 16) & 1u)) >> 16;
    return ur | (ui << 16);
}

// system-scope (LLC) 8B load — used only for the final Sm read after atomics
__device__ __forceinline__ float2 ld_sys(const float2* p) {
    unsigned long long v = __hip_atomic_load((const unsigned long long*)p,
                                 __ATOMIC_RELAXED, __HIP_MEMORY_SCOPE_SYSTEM);
    union { unsigned long long u; float2 f; } c; c.u = v; return c.f;
}

__device__ __forceinline__ float block_reduce(float v, float* red, int tid) {
    red[tid] = v;
    __syncthreads();
    for (int off = 128; off > 0; off >>= 1) {
        if (tid < off) red[tid] += red[tid + off];
        __syncthreads();
    }
    float r = red[0];
    __syncthreads();
    return r;
}

// Barrier-free complex inner product over one 128-row LDS chunk.
__device__ __forceinline__ void cmul_inner(const unsigned int* __restrict__ sBu,
                                           const float2 (*__restrict__ sQ)[8],
                                           int w, int lane, float acc[8]) {
    #pragma unroll 8
    for (int kk = 0; kk < 128; ++kk) {
        float4 qv = *(const float4*)&sQ[kk][2 * w];
        uint2 bu = *(const uint2*)&sBu[(kk << 7) + 2 * lane];
        float b0r = __uint_as_float(bu.x << 16);
        float b0i = __uint_as_float(bu.x & 0xffff0000u);
        float b1r = __uint_as_float(bu.y << 16);
        float b1i = __uint_as_float(bu.y & 0xffff0000u);
        acc[0] += qv.x * b0r - qv.y * b0i;  acc[1] += qv.x * b0i + qv.y * b0r;
        acc[2] += qv.x * b1r - qv.y * b1i;  acc[3] += qv.x * b1i + qv.y * b1r;
        acc[4] += qv.z * b0r - qv.w * b0i;  acc[5] += qv.z * b0i + qv.w * b0r;
        acc[6] += qv.z * b1r - qv.w * b1i;  acc[7] += qv.z * b1i + qv.w * b1r;
    }
}

// Full-K GEMM for one 8x128 output tile: K = NCH*128, chunked 128 rows at a
// time through LDS. Q fp32 (split r/i arrays or float2 buffer); B bf16
// (converted on-the-fly from fp32 pair, or copied from a packed table).
template<int NCH, bool QSPLIT, bool BCONV>
__device__ __forceinline__ void gemm_block(
    const float* __restrict__ Qr_, const float* __restrict__ Qi_,
    const float2* __restrict__ Qf, int Wq,
    const float* __restrict__ Br_, const float* __restrict__ Bi_,
    const unsigned int* __restrict__ Bb, int Wb,
    int c0, int rg, unsigned int* sBu, float2 (*sQ)[8], float acc[8]) {
    const int tid = threadIdx.x;
    const int w = tid >> 6, lane = tid & 63;
    #pragma unroll 1
    for (int ch = 0; ch < NCH; ++ch) {
        if (ch) __syncthreads();         // prior chunk's readers done
        const int kk0 = ch * 128;
        if constexpr (BCONV) {
            for (int slot = tid; slot < 4096; slot += 256) {
                int row = slot >> 5, cq = (slot & 31) << 2;
                int g = (kk0 + row) * Wb + c0 + cq;
                float4 vr = *(const float4*)&Br_[g];
                float4 vi = *(const float4*)&Bi_[g];
                *(uint4*)&sBu[(row << 7) + cq] = make_uint4(
                    f2bf2(vr.x, vi.x), f2bf2(vr.y, vi.y),
                    f2bf2(vr.z, vi.z), f2bf2(vr.w, vi.w));
            }
        } else {
            for (int slot = tid; slot < 4096; slot += 256) {
                int row = slot >> 5, cq = (slot & 31) << 2;
                *(uint4*)&sBu[(row << 7) + cq] =
                    *(const uint4*)&Bb[(kk0 + row) * Wb + c0 + cq];
            }
        }
        for (int slot = tid; slot < 1024; slot += 256) {
            int row = slot >> 7, kk = slot & 127;
            int g = (rg * 8 + row) * Wq + kk0 + kk;
            if constexpr (QSPLIT) sQ[kk][row] = make_float2(Qr_[g], Qi_[g]);
            else                  sQ[kk][row] = Qf[g];
        }
        __syncthreads();
        cmul_inner(sBu, sQ, w, lane, acc);
    }
}

__device__ __forceinline__ void st_f(float2* O, int W, int prow, int pcol,
                                     const float acc[8]) {
    *(float4*)&O[prow * W + pcol]       = make_float4(acc[0], acc[1], acc[2], acc[3]);
    *(float4*)&O[(prow + 1) * W + pcol] = make_float4(acc[4], acc[5], acc[6], acc[7]);
}
__device__ __forceinline__ void st_b(unsigned int* O, int W, int prow, int pcol,
                                     const float acc[8]) {
    *(uint2*)&O[prow * W + pcol]       = make_uint2(f2bf2(acc[0], acc[1]), f2bf2(acc[2], acc[3]));
    *(uint2*)&O[(prow + 1) * W + pcol] = make_uint2(f2bf2(acc[4], acc[5]), f2bf2(acc[6], acc[7]));
}

// ---------------- P1: AF2(+b), G1, A2(+b), H1, copies -----------------------
// [0,144): AF2 48x3  [144,192): G1 16x3  [192,256): A2 32x2  [256,288): H1 16x2
// [288,304): copies G0=CF, H0=C, Sm=DF
__global__ __launch_bounds__(256, 2)
void p1_kernel(Params P) {
    __shared__ __align__(16) unsigned int sBu[128 * 128];  // 64 KB
    __shared__ __align__(16) float2 sQ[128][8];            // 8 KB
    const int b = blockIdx.x, tid = threadIdx.x;
    const int w = tid >> 6, lane = tid & 63;
    float acc[8] = {};
    if (b < 144) {
        int rg = b / 3, cs = b - 3 * rg;
        gemm_block<3, true, true>(P.AFr, P.AFi, nullptr, 384, P.AFr, P.AFi, nullptr, 384,
                                  cs << 7, rg, sBu, sQ, acc);
        const int prow = rg * 8 + 2 * w, pcol = (cs << 7) + 2 * lane;
        st_f(P.AF2f, 384, prow, pcol, acc);
        st_b(P.AF2b, 384, prow, pcol, acc);
    } else if (b < 192) {
        int u = b - 144, rg = u / 3, cs = u - 3 * (u / 3);
        gemm_block<3, true, true>(P.CFr, P.CFi, nullptr, 384, P.AFr, P.AFi, nullptr, 384,
                                  cs << 7, rg, sBu, sQ, acc);
        const int prow = rg * 8 + 2 * w, pcol = (cs << 7) + 2 * lane;
        st_f(P.Gf + 128 * 384, 384, prow, pcol, acc);        // G1 -> G rows 128..255
    } else if (b < 256) {
        int u = b - 192, rg = u >> 1, cs = u & 1;
        gemm_block<2, true, true>(P.Ar, P.Ai, nullptr, 256, P.Ar, P.Ai, nullptr, 256,
                                  cs << 7, rg, sBu, sQ, acc);
        const int prow = rg * 8 + 2 * w, pcol = (cs << 7) + 2 * lane;
        st_f(P.A2f, 256, prow, pcol, acc);
        st_b(P.A2b, 256, prow, pcol, acc);
    } else if (b < 288) {
        int u = b - 256, rg = u >> 1, cs = u & 1;
        gemm_block<2, true, true>(P.Cr, P.Ci, nullptr, 256, P.Ar, P.Ai, nullptr, 256,
                                  cs << 7, rg, sBu, sQ, acc);
        const int prow = rg * 8 + 2 * w, pcol = (cs << 7) + 2 * lane;
        st_f(P.Hf + 128 * 256, 256, prow, pcol, acc);        // H1 -> H rows 128..255
    } else {
        for (int i = (b - 288) * 256 + tid; i < 98304; i += 16 * 256) {
            if (i < 49152)       P.Gf[i] = make_float2(P.CFr[i], P.CFi[i]);       // G0
            else if (i < 81920) { int j = i - 49152; P.Hf[j] = make_float2(P.Cr[j], P.Ci[j]); } // H0
            else                { int j = i - 81920; P.Sm[j] = make_float2(P.DFr[j], P.DFi[j]); }
        }
    }
}

// ---------------- P2: AF4b, [G2;G3], A4b, [H2;H3] ---------------------------
// [0,144): AF4b 48x3  [144,240): G23 32x3  [240,304): A4b 32x2  [304,368): H23 32x2
__global__ __launch_bounds__(256, 2)
void p2_kernel(Params P) {
    __shared__ __align__(16) unsigned int sBu[128 * 128];
    __shared__ __align__(16) float2 sQ[128][8];
    const int b = blockIdx.x, tid = threadIdx.x;
    const int w = tid >> 6, lane = tid & 63;
    float acc[8] = {};
    if (b < 144) {
        int rg = b / 3, cs = b - 3 * rg;
        gemm_block<3, false, false>(nullptr, nullptr, P.AF2f, 384, nullptr, nullptr, P.AF2b, 384,
                                    cs << 7, rg, sBu, sQ, acc);
        const int prow = rg * 8 + 2 * w, pcol = (cs << 7) + 2 * lane;
        st_b(P.AF4b, 384, prow, pcol, acc);
    } else if (b < 240) {
        int u = b - 144, rg = u / 3, cs = u - 3 * (u / 3);    // rg 0..31 -> Q rows 0..255
        gemm_block<3, false, false>(nullptr, nullptr, P.Gf, 384, nullptr, nullptr, P.AF2b, 384,
                                    cs << 7, rg, sBu, sQ, acc);
        const int prow = rg * 8 + 2 * w, pcol = (cs << 7) + 2 * lane;
        st_f(P.Gf + 256 * 384, 384, prow, pcol, acc);        // G2,G3 -> rows 256..511
    } else if (b < 304) {
        int u = b - 240, rg = u >> 1, cs = u & 1;
        gemm_block<2, false, false>(nullptr, nullptr, P.A2f, 256, nullptr, nullptr, P.A2b, 256,
                                    cs << 7, rg, sBu, sQ, acc);
        const int prow = rg * 8 + 2 * w, pcol = (cs << 7) + 2 * lane;
        st_b(P.A4b, 256, prow, pcol, acc);
    } else {
        int u = b - 304, rg = u >> 1, cs = u & 1;             // rg 0..31
        gemm_block<2, false, false>(nullptr, nullptr, P.Hf, 256, nullptr, nullptr, P.A2b, 256,
                                    cs << 7, rg, sBu, sQ, acc);
        const int prow = rg * 8 + 2 * w, pcol = (cs << 7) + 2 * lane;
        st_f(P.Hf + 256 * 256, 256, prow, pcol, acc);        // H2,H3 -> rows 256..511
    }
}

// ---------------- P3: [G4..G7], [H4..H7] ------------------------------------
// [0,192): G4567 64x3   [192,320): H4567 64x2
__global__ __launch_bounds__(256, 2)
void p3_kernel(Params P) {
    __shared__ __align__(16) unsigned int sBu[128 * 128];
    __shared__ __align__(16) float2 sQ[128][8];
    const int b = blockIdx.x, tid = threadIdx.x;
    const int w = tid >> 6, lane = tid & 63;
    float acc[8] = {};
    if (b < 192) {
        int rg = b / 3, cs = b - 3 * (b / 3);                 // rg 0..63 -> Q rows 0..511
        gemm_block<3, false, false>(nullptr, nullptr, P.Gf, 384, nullptr, nullptr, P.AF4b, 384,
                                    cs << 7, rg, sBu, sQ, acc);
        const int prow = rg * 8 + 2 * w, pcol = (cs << 7) + 2 * lane;
        st_f(P.Gf + 512 * 384, 384, prow, pcol, acc);        // G4..7 -> rows 512..1023
    } else {
        int u = b - 192, rg = u >> 1, cs = u & 1;             // rg 0..63
        gemm_block<2, false, false>(nullptr, nullptr, P.Hf, 256, nullptr, nullptr, P.A4b, 256,
                                    cs << 7, rg, sBu, sQ, acc);
        const int prow = rg * 8 + 2 * w, pcol = (cs << 7) + 2 * lane;
        st_f(P.Hf + 512 * 256, 256, prow, pcol, acc);        // H4..7 -> rows 512..1023
    }
}

// ---------------- P4: E + reductions + ticketed finalize --------------------
// 128 blocks, rg = b (E rows rg*8..rg*8+7 of the 1024-row stack).
__global__ __launch_bounds__(256, 2)
void p4_kernel(Params P) {
    __shared__ __align__(16) unsigned int sBu[128 * 128];
    __shared__ __align__(16) float2 sQ[128][8];
    __shared__ float red[256];
    __shared__ int lastf;
    const int b = blockIdx.x, tid = threadIdx.x;
    const int w = tid >> 6, lane = tid & 63;
    float acc[8] = {};
    gemm_block<3, false, true>(nullptr, nullptr, P.Gf, 384, P.BFr, P.BFi, nullptr, 128,
                               0, b, sBu, sQ, acc);
    const int prow = b * 8 + 2 * w, pcol = 2 * lane;
    // E = G*BF - H[:, :128]
    float2 h00 = P.Hf[prow * 256 + pcol],       h01 = P.Hf[prow * 256 + pcol + 1];
    float2 h10 = P.Hf[(prow + 1) * 256 + pcol], h11 = P.Hf[(prow + 1) * 256 + pcol + 1];
    float e0r = acc[0] - h00.x, e0i = acc[1] - h00.y;
    float e1r = acc[2] - h01.x, e1i = acc[3] - h01.y;
    float e2r = acc[4] - h10.x, e2i = acc[5] - h10.y;
    float e3r = acc[6] - h11.x, e3i = acc[7] - h11.y;
    float t1 = e0r * e0r + e0i * e0i + e1r * e1r + e1i * e1i
             + e2r * e2r + e2i * e2i + e3r * e3r + e3i * e3i;
    t1 = block_reduce(t1, red, tid);
    if (tid == 0) atomicAdd(P.S1, t1);
    // Sm += E  (Sm indexed by (p = row mod 128, m))
    float* SmF = (float*)P.Sm;
    const int p0 = prow & 127, p1 = (prow + 1) & 127;
    atomicAdd(&SmF[(p0 * 128 + pcol) * 2],     e0r); atomicAdd(&SmF[(p0 * 128 + pcol) * 2 + 1],     e0i);
    atomicAdd(&SmF[(p0 * 128 + pcol + 1) * 2], e1r); atomicAdd(&SmF[(p0 * 128 + pcol + 1) * 2 + 1], e1i);
    atomicAdd(&SmF[(p1 * 128 + pcol) * 2],     e2r); atomicAdd(&SmF[(p1 * 128 + pcol) * 2 + 1],     e2i);
    atomicAdd(&SmF[(p1 * 128 + pcol + 1) * 2], e3r); atomicAdd(&SmF[(p1 * 128 + pcol + 1) * 2 + 1], e3i);
    __syncthreads();   // implicit vmcnt(0) drain: all this block's atomics done
    if (tid == 0) lastf = (atomicAdd(P.tick, 1u) == 127u) ? 1 : 0;
    __syncthreads();
    if (lastf) {       // all 128 blocks' atomics are at the coherence point
        float s2 = 0.f, sd = 0.f;
        for (int i = tid; i < 16384; i += 256) {
            float2 sm = ld_sys(&P.Sm[i]);
            s2 += sm.x * sm.x + sm.y * sm.y;
            float dr = P.DFr[i], di = P.DFi[i];
            sd += dr * dr + di * di;
        }
        s2 = block_reduce(s2, red, tid);
        sd = block_reduce(sd, red, tid);
        if (tid == 0) {
            float s1 = atomicAdd(P.S1, 0.f);
            P.out[0] = (99.0f * (s1 + sd) + s2) / 100.0f;
        }
    }
}

extern "C" void kernel_launch(void* const* d_in, const int* in_sizes, int n_in,
                              void* d_out, int out_size, void* d_ws, size_t ws_size,
                              hipStream_t stream) {
    (void)in_sizes; (void)n_in; (void)out_size; (void)ws_size;
    char* ws = (char*)d_ws;
    Params h;
    h.Cr  = (const float*)d_in[0];
    h.Ci  = (const float*)d_in[1];
    h.Ar  = (const float*)d_in[2];
    h.Ai  = (const float*)d_in[3];
    h.AFr = (const float*)d_in[4];
    h.AFi = (const float*)d_in[5];
    h.BFr = (const float*)d_in[6];
    h.BFi = (const float*)d_in[7];
    h.CFr = (const float*)d_in[8];
    h.CFi = (const float*)d_in[9];
    h.DFr = (const float*)d_in[10];
    h.DFi = (const float*)d_in[11];
    h.Gf   = (float2*)(ws + 0);                  // 1024x384 c64 = 3145728 B
    h.Hf   = (float2*)(ws + 3145728);            // 1024x256 c64 = 2097152 B
    h.AF2f = (float2*)(ws + 5242880);            // 384x384 c64  = 1179648 B
    h.A2f  = (float2*)(ws + 6422528);            // 256x256 c64  =  524288 B
    h.AF2b = (unsigned int*)(ws + 6946816);      // 384x384 u32  =  589824 B
    h.AF4b = (unsigned int*)(ws + 7536640);      //               589824 B
    h.A2b  = (unsigned int*)(ws + 8126464);      // 256x256 u32  =  262144 B
    h.A4b  = (unsigned int*)(ws + 8388608);      //               262144 B
    h.Sm   = (float2*)(ws + 8650752);            // 128x128 c64  =  131072 B
    h.S1   = (float*)(ws + 8781824);
    h.tick = (unsigned int*)(ws + 8781828);
    h.out  = (float*)d_out;

    hipMemsetAsync(ws + 8781824, 0, 8, stream);  // S1, tick
    p1_kernel<<<304, 256, 0, stream>>>(h);
    p2_kernel<<<368, 256, 0, stream>>>(h);
    p3_kernel<<<320, 256, 0, stream>>>(h);
    p4_kernel<<<128, 256, 0, stream>>>(h);
}

// Round 6
// 221.569 us; speedup vs baseline: 2.2429x; 1.1748x over previous
//
#include <hip/hip_runtime.h>

// obj = (99*sum_t ||c_t||^2 + ||sum_t c_t||^2)/100 (Parseval over the 100
// samples = 99th roots of unity, z=1 double-counted), c_0 = D_F,
// c_{k+1} = E_k = C_F A_F^k B_F - C A^k B, B = eye(256,128), k=0..7.
//
// POWER-DOUBLING dataflow (verified correct in round 5, absmax 0.0):
//   P1: AF2=AF*AF, G1=CF*AF, A2=A*A, H1=C*A  (+ copies G0=CF,H0=C,Sm=DF)
//   P2: AF4b=bf16(AF2*AF2b), [G2;G3]=[G0;G1]*AF2b, A4b, [H2;H3]
//   P3: [G4..G7]=[G0..G3]*AF4b, [H4..H7]=[H0..H3]*A4b
//   P4: E=[G0..G7]*BFb - H[:,:128]; S1+=|E|^2; Sm+=E; ticketed finalize.
// Round-5 post-mortem: kernels were latency-bound (VALUBusy 12%, occupancy
// 3.7%): 128-368 blocks x 73.5 KB LDS -> ~1 wave/SIMD. This revision keeps
// the dataflow and RETILES for occupancy: 8x64 (P4: 4x64) output tiles,
// K chunked 64 through LDS -> 20 KB LDS, __launch_bounds__(256,4) -> 4
// blocks/CU = 4 waves/SIMD; 512-736 blocks per kernel. bf16 pack via
// single-inst v_cvt_pk_bf16_f32 (low=real, high=imag, RNE — same as before).

struct Params {
    const float *AFr, *AFi, *Ar, *Ai, *BFr, *BFi, *CFr, *CFi, *Cr, *Ci, *DFr, *DFi;
    float2 *Gf, *Hf, *AF2f, *A2f, *Sm;          // fp32 complex buffers
    unsigned int *AF2b, *AF4b, *A2b, *A4b;      // packed bf16 tables
    float *S1; unsigned int *tick; float *out;
};

__device__ __forceinline__ unsigned int pk_bf16(float r, float i) {
    unsigned int u;
    asm("v_cvt_pk_bf16_f32 %0, %1, %2" : "=v"(u) : "v"(r), "v"(i));
    return u;   // low16 = bf16(r), high16 = bf16(i)
}

// system-scope (LLC) 8B load — used only for the final Sm read after atomics
__device__ __forceinline__ float2 ld_sys(const float2* p) {
    unsigned long long v = __hip_atomic_load((const unsigned long long*)p,
                                 __ATOMIC_RELAXED, __HIP_MEMORY_SCOPE_SYSTEM);
    union { unsigned long long u; float2 f; } c; c.u = v; return c.f;
}

__device__ __forceinline__ float block_reduce(float v, float* red, int tid) {
    red[tid] = v;
    __syncthreads();
    for (int off = 128; off > 0; off >>= 1) {
        if (tid < off) red[tid] += red[tid + off];
        __syncthreads();
    }
    float r = red[0];
    __syncthreads();
    return r;
}

// ---- GEMM: out tile ROWS x 64 at (rg*ROWS, c0), K = NCH*64 chunked via LDS.
// Q fp32 (split r/i arrays or float2 buffer); B bf16-packed (converted
// on-the-fly from fp32 pair, or read from a packed table). acc: 2*(ROWS/4).
template<int NCH, int ROWS, bool QSPLIT, bool BCONV>
__device__ __forceinline__ void gemm64(
    const float* __restrict__ Qr_, const float* __restrict__ Qi_,
    const float2* __restrict__ Qf, int Wq,
    const float* __restrict__ Br_, const float* __restrict__ Bi_,
    const unsigned int* __restrict__ Bb, int Wb,
    int c0, int rg, unsigned int* sBu, float2* sQ, float* acc) {
    const int tid = threadIdx.x;
    const int w = tid >> 6, lane = tid & 63;
    constexpr int RPW = ROWS / 4;    // rows per wave (2 or 1)
    #pragma unroll 1
    for (int ch = 0; ch < NCH; ++ch) {
        if (ch) __syncthreads();                 // prior chunk's readers done
        const int kk0 = ch * 64;
        if constexpr (BCONV) {
            for (int slot = tid; slot < 1024; slot += 256) {   // 64 x 16 quads
                int row = slot >> 4, cq = (slot & 15) << 2;
                int g = (kk0 + row) * Wb + c0 + cq;
                float4 vr = *(const float4*)&Br_[g];
                float4 vi = *(const float4*)&Bi_[g];
                *(uint4*)&sBu[(row << 6) + cq] = make_uint4(
                    pk_bf16(vr.x, vi.x), pk_bf16(vr.y, vi.y),
                    pk_bf16(vr.z, vi.z), pk_bf16(vr.w, vi.w));
            }
        } else {
            for (int slot = tid; slot < 1024; slot += 256) {
                int row = slot >> 4, cq = (slot & 15) << 2;
                *(uint4*)&sBu[(row << 6) + cq] =
                    *(const uint4*)&Bb[(kk0 + row) * Wb + c0 + cq];
            }
        }
        for (int slot = tid; slot < 64 * ROWS; slot += 256) {
            int row = slot >> 6, kk = slot & 63;
            int g = (rg * ROWS + row) * Wq + kk0 + kk;
            float2 q = QSPLIT ? make_float2(Qr_[g], Qi_[g]) : Qf[g];
            sQ[kk * ROWS + row] = q;
        }
        __syncthreads();
        #pragma unroll 8
        for (int kk = 0; kk < 64; ++kk) {
            unsigned int bu = sBu[(kk << 6) + lane];
            float br = __uint_as_float(bu << 16);
            float bi = __uint_as_float(bu & 0xffff0000u);
            if constexpr (RPW == 2) {
                float4 qv = *(const float4*)&sQ[kk * ROWS + 2 * w];
                acc[0] += qv.x * br - qv.y * bi;  acc[1] += qv.x * bi + qv.y * br;
                acc[2] += qv.z * br - qv.w * bi;  acc[3] += qv.z * bi + qv.w * br;
            } else {
                float2 qv = sQ[kk * ROWS + w];
                acc[0] += qv.x * br - qv.y * bi;  acc[1] += qv.x * bi + qv.y * br;
            }
        }
    }
}

// epilogues: thread (w,lane) owns rows {rg*8+2w, +1}, col c0+lane
__device__ __forceinline__ void st_f8(float2* O, int W, int prow, int pcol,
                                      const float acc[4]) {
    O[prow * W + pcol]       = make_float2(acc[0], acc[1]);
    O[(prow + 1) * W + pcol] = make_float2(acc[2], acc[3]);
}
__device__ __forceinline__ void st_b8(unsigned int* O, int W, int prow, int pcol,
                                      const float acc[4]) {
    O[prow * W + pcol]       = pk_bf16(acc[0], acc[1]);
    O[(prow + 1) * W + pcol] = pk_bf16(acc[2], acc[3]);
}

// ---------------- P1: AF2(+b), G1, A2(+b), H1, copies -----------------------
// [0,288): AF2 48rg x 6cs   [288,384): G1 16x6   [384,512): A2 32x4
// [512,576): H1 16x4        [576,592): copies G0=CF, H0=C, Sm=DF
__global__ __launch_bounds__(256, 4)
void p1_kernel(Params P) {
    __shared__ __align__(16) unsigned int sBu[64 * 64];  // 16 KB
    __shared__ __align__(16) float2 sQ[64 * 8];          // 4 KB
    const int b = blockIdx.x, tid = threadIdx.x;
    const int w = tid >> 6, lane = tid & 63;
    float acc[4] = {};
    if (b < 288) {
        int rg = b / 6, cs = b - 6 * rg;
        gemm64<6, 8, true, true>(P.AFr, P.AFi, nullptr, 384, P.AFr, P.AFi, nullptr, 384,
                                 cs << 6, rg, sBu, sQ, acc);
        const int prow = rg * 8 + 2 * w, pcol = (cs << 6) + lane;
        st_f8(P.AF2f, 384, prow, pcol, acc);
        st_b8(P.AF2b, 384, prow, pcol, acc);
    } else if (b < 384) {
        int u = b - 288, rg = u / 6, cs = u - 6 * rg;
        gemm64<6, 8, true, true>(P.CFr, P.CFi, nullptr, 384, P.AFr, P.AFi, nullptr, 384,
                                 cs << 6, rg, sBu, sQ, acc);
        st_f8(P.Gf + 128 * 384, 384, rg * 8 + 2 * w, (cs << 6) + lane, acc);  // G1
    } else if (b < 512) {
        int u = b - 384, rg = u >> 2, cs = u & 3;
        gemm64<4, 8, true, true>(P.Ar, P.Ai, nullptr, 256, P.Ar, P.Ai, nullptr, 256,
                                 cs << 6, rg, sBu, sQ, acc);
        const int prow = rg * 8 + 2 * w, pcol = (cs << 6) + lane;
        st_f8(P.A2f, 256, prow, pcol, acc);
        st_b8(P.A2b, 256, prow, pcol, acc);
    } else if (b < 576) {
        int u = b - 512, rg = u >> 2, cs = u & 3;
        gemm64<4, 8, true, true>(P.Cr, P.Ci, nullptr, 256, P.Ar, P.Ai, nullptr, 256,
                                 cs << 6, rg, sBu, sQ, acc);
        st_f8(P.Hf + 128 * 256, 256, rg * 8 + 2 * w, (cs << 6) + lane, acc);  // H1
    } else {
        for (int i = (b - 576) * 256 + tid; i < 98304; i += 16 * 256) {
            if (i < 49152)       P.Gf[i] = make_float2(P.CFr[i], P.CFi[i]);
            else if (i < 81920) { int j = i - 49152; P.Hf[j] = make_float2(P.Cr[j], P.Ci[j]); }
            else                { int j = i - 81920; P.Sm[j] = make_float2(P.DFr[j], P.DFi[j]); }
        }
    }
}

// ---------------- P2: AF4b, [G2;G3], A4b, [H2;H3] ---------------------------
// [0,288): AF4b 48x6  [288,480): G23 32x6  [480,608): A4b 32x4  [608,736): H23 32x4
__global__ __launch_bounds__(256, 4)
void p2_kernel(Params P) {
    __shared__ __align__(16) unsigned int sBu[64 * 64];
    __shared__ __align__(16) float2 sQ[64 * 8];
    const int b = blockIdx.x, tid = threadIdx.x;
    const int w = tid >> 6, lane = tid & 63;
    float acc[4] = {};
    if (b < 288) {
        int rg = b / 6, cs = b - 6 * rg;
        gemm64<6, 8, false, false>(nullptr, nullptr, P.AF2f, 384, nullptr, nullptr, P.AF2b, 384,
                                   cs << 6, rg, sBu, sQ, acc);
        st_b8(P.AF4b, 384, rg * 8 + 2 * w, (cs << 6) + lane, acc);
    } else if (b < 480) {
        int u = b - 288, rg = u / 6, cs = u - 6 * rg;        // rg 0..31 (G0,G1 rows)
        gemm64<6, 8, false, false>(nullptr, nullptr, P.Gf, 384, nullptr, nullptr, P.AF2b, 384,
                                   cs << 6, rg, sBu, sQ, acc);
        st_f8(P.Gf + 256 * 384, 384, rg * 8 + 2 * w, (cs << 6) + lane, acc);  // G2,G3
    } else if (b < 608) {
        int u = b - 480, rg = u >> 2, cs = u & 3;
        gemm64<4, 8, false, false>(nullptr, nullptr, P.A2f, 256, nullptr, nullptr, P.A2b, 256,
                                   cs << 6, rg, sBu, sQ, acc);
        st_b8(P.A4b, 256, rg * 8 + 2 * w, (cs << 6) + lane, acc);
    } else {
        int u = b - 608, rg = u >> 2, cs = u & 3;            // rg 0..31 (H0,H1 rows)
        gemm64<4, 8, false, false>(nullptr, nullptr, P.Hf, 256, nullptr, nullptr, P.A2b, 256,
                                   cs << 6, rg, sBu, sQ, acc);
        st_f8(P.Hf + 256 * 256, 256, rg * 8 + 2 * w, (cs << 6) + lane, acc);  // H2,H3
    }
}

// ---------------- P3: [G4..G7], [H4..H7] ------------------------------------
// [0,384): G4567 64x6    [384,640): H4567 64x4
__global__ __launch_bounds__(256, 4)
void p3_kernel(Params P) {
    __shared__ __align__(16) unsigned int sBu[64 * 64];
    __shared__ __align__(16) float2 sQ[64 * 8];
    const int b = blockIdx.x, tid = threadIdx.x;
    const int w = tid >> 6, lane = tid & 63;
    float acc[4] = {};
    if (b < 384) {
        int rg = b / 6, cs = b - 6 * rg;                     // rg 0..63 (G0..G3 rows)
        gemm64<6, 8, false, false>(nullptr, nullptr, P.Gf, 384, nullptr, nullptr, P.AF4b, 384,
                                   cs << 6, rg, sBu, sQ, acc);
        st_f8(P.Gf + 512 * 384, 384, rg * 8 + 2 * w, (cs << 6) + lane, acc);  // G4..7
    } else {
        int u = b - 384, rg = u >> 2, cs = u & 3;            // rg 0..63 (H0..H3 rows)
        gemm64<4, 8, false, false>(nullptr, nullptr, P.Hf, 256, nullptr, nullptr, P.A4b, 256,
                                   cs << 6, rg, sBu, sQ, acc);
        st_f8(P.Hf + 512 * 256, 256, rg * 8 + 2 * w, (cs << 6) + lane, acc);  // H4..7
    }
}

// ---------------- P4: E + reductions + ticketed finalize --------------------
// 512 blocks: rg = b>>1 (4-row groups of the 1024-row stack), cs = b&1.
__global__ __launch_bounds__(256, 4)
void p4_kernel(Params P) {
    __shared__ __align__(16) unsigned int sBu[64 * 64];
    __shared__ __align__(16) float2 sQ[64 * 4];
    __shared__ float red[256];
    __shared__ int lastf;
    const int b = blockIdx.x, tid = threadIdx.x;
    const int w = tid >> 6, lane = tid & 63;
    const int rg = b >> 1, c0 = (b & 1) << 6;
    float acc[2] = {};
    gemm64<6, 4, false, true>(nullptr, nullptr, P.Gf, 384, P.BFr, P.BFi, nullptr, 128,
                              c0, rg, sBu, sQ, acc);
    const int prow = rg * 4 + w, col = c0 + lane;
    float2 hv = P.Hf[prow * 256 + col];                      // H[:, :128]
    float er = acc[0] - hv.x, ei = acc[1] - hv.y;
    float t1 = block_reduce(er * er + ei * ei, red, tid);
    if (tid == 0) atomicAdd(P.S1, t1);
    float* SmF = (float*)P.Sm;
    int si = (((prow & 127) << 7) + col) << 1;
    atomicAdd(&SmF[si], er);
    atomicAdd(&SmF[si + 1], ei);
    __syncthreads();
    if (tid == 0) lastf = (atomicAdd(P.tick, 1u) == 511u) ? 1 : 0;
    __syncthreads();
    if (lastf) {   // all other blocks' atomics are at the coherence point
        float s2 = 0.f, sd = 0.f;
        for (int i = tid; i < 16384; i += 256) {
            float2 sm = ld_sys(&P.Sm[i]);
            s2 += sm.x * sm.x + sm.y * sm.y;
            float dr = P.DFr[i], di = P.DFi[i];
            sd += dr * dr + di * di;
        }
        s2 = block_reduce(s2, red, tid);
        sd = block_reduce(sd, red, tid);
        if (tid == 0) {
            float s1 = atomicAdd(P.S1, 0.f);
            P.out[0] = (99.0f * (s1 + sd) + s2) / 100.0f;
        }
    }
}

extern "C" void kernel_launch(void* const* d_in, const int* in_sizes, int n_in,
                              void* d_out, int out_size, void* d_ws, size_t ws_size,
                              hipStream_t stream) {
    (void)in_sizes; (void)n_in; (void)out_size; (void)ws_size;
    char* ws = (char*)d_ws;
    Params h;
    h.Cr  = (const float*)d_in[0];
    h.Ci  = (const float*)d_in[1];
    h.Ar  = (const float*)d_in[2];
    h.Ai  = (const float*)d_in[3];
    h.AFr = (const float*)d_in[4];
    h.AFi = (const float*)d_in[5];
    h.BFr = (const float*)d_in[6];
    h.BFi = (const float*)d_in[7];
    h.CFr = (const float*)d_in[8];
    h.CFi = (const float*)d_in[9];
    h.DFr = (const float*)d_in[10];
    h.DFi = (const float*)d_in[11];
    h.Gf   = (float2*)(ws + 0);                  // 1024x384 c64 = 3145728 B
    h.Hf   = (float2*)(ws + 3145728);            // 1024x256 c64 = 2097152 B
    h.AF2f = (float2*)(ws + 5242880);            // 384x384 c64  = 1179648 B
    h.A2f  = (float2*)(ws + 6422528);            // 256x256 c64  =  524288 B
    h.AF2b = (unsigned int*)(ws + 6946816);      // 384x384 u32  =  589824 B
    h.AF4b = (unsigned int*)(ws + 7536640);      //               589824 B
    h.A2b  = (unsigned int*)(ws + 8126464);      // 256x256 u32  =  262144 B
    h.A4b  = (unsigned int*)(ws + 8388608);      //               262144 B
    h.Sm   = (float2*)(ws + 8650752);            // 128x128 c64  =  131072 B
    h.S1   = (float*)(ws + 8781824);
    h.tick = (unsigned int*)(ws + 8781828);
    h.out  = (float*)d_out;

    hipMemsetAsync(ws + 8781824, 0, 8, stream);  // S1, tick
    p1_kernel<<<592, 256, 0, stream>>>(h);
    p2_kernel<<<736, 256, 0, stream>>>(h);
    p3_kernel<<<640, 256, 0, stream>>>(h);
    p4_kernel<<<512, 256, 0, stream>>>(h);
}